// Round 3
// baseline (118.363 us; speedup 1.0000x reference)
//
#include <hip/hip_runtime.h>
#include <hip/hip_bf16.h>
#include <stdint.h>

#define NB 2
#define SEQ 4096
#define HID 256
#define NHEAD 8
#define NKVH 4
#define HDIM 32

typedef __bf16 bf16;
typedef __bf16 bf16x8 __attribute__((ext_vector_type(8)));
typedef float f32x4 __attribute__((ext_vector_type(4)));

static __device__ __forceinline__ uint16_t bfbits(float f) {
    bf16 h = (bf16)f;
    return __builtin_bit_cast(uint16_t, h);
}
static __device__ __forceinline__ uint32_t pack_bf16(float lo, float hi) {
    return (uint32_t)bfbits(lo) | ((uint32_t)bfbits(hi) << 16);
}
// raw v_exp_f32: no libm range wrapper.  exp2(-1e30) == +0 in HW.
static __device__ __forceinline__ float fexp2(float x) {
#if __has_builtin(__builtin_amdgcn_exp2f)
    return __builtin_amdgcn_exp2f(x);
#else
    float r; asm("v_exp_f32 %0, %1" : "=v"(r) : "v"(x)); return r;
#endif
}

// ---------------------------------------------------------------------------
// Kernel 1: QKV projection + RoPE (unchanged from R2).
// ---------------------------------------------------------------------------
__global__ __launch_bounds__(256) void qkv_proj(
    const float* __restrict__ hs, const float* __restrict__ Wq,
    const float* __restrict__ Wk, const float* __restrict__ Wv,
    bf16* __restrict__ qws, bf16* __restrict__ kws, bf16* __restrict__ vtws)
{
    __shared__ bf16 As[64][136];
    __shared__ bf16 Bs[64][136];
    const int t = threadIdx.x;
    const int wid = t >> 6, lane = t & 63;
    const int g = lane >> 4, c = lane & 15;
    const int n0 = blockIdx.x * 64;
    const int m0 = blockIdx.y * 64;

    const float* bsrc; int ro;
    if (n0 < 256)      { bsrc = Wq; ro = n0; }
    else if (n0 < 384) { bsrc = Wk; ro = n0 - 256; }
    else               { bsrc = Wv; ro = n0 - 384; }

    const f32x4 zf = {0.f, 0.f, 0.f, 0.f};
    f32x4 acc[4] = {zf, zf, zf, zf};

    const int c4 = t & 31;
    const int rb = t >> 5;

    for (int ks = 0; ks < 256; ks += 128) {
        __syncthreads();
        #pragma unroll
        for (int i = 0; i < 8; ++i) {
            int row = i * 8 + rb;
            float4 v = *(const float4*)&hs[(size_t)(m0 + row) * HID + ks + c4 * 4];
            ushort4 w; w.x = bfbits(v.x); w.y = bfbits(v.y); w.z = bfbits(v.z); w.w = bfbits(v.w);
            *(ushort4*)&As[row][c4 * 4] = w;
        }
        #pragma unroll
        for (int i = 0; i < 8; ++i) {
            int row = i * 8 + rb;
            float4 v = *(const float4*)&bsrc[(size_t)(ro + row) * HID + ks + c4 * 4];
            ushort4 w; w.x = bfbits(v.x); w.y = bfbits(v.y); w.z = bfbits(v.z); w.w = bfbits(v.w);
            *(ushort4*)&Bs[row][c4 * 4] = w;
        }
        __syncthreads();
        #pragma unroll
        for (int kk = 0; kk < 128; kk += 32) {
            bf16x8 af = *(const bf16x8*)&As[wid * 16 + c][kk + g * 8];
            #pragma unroll
            for (int nt = 0; nt < 4; ++nt) {
                bf16x8 bfr = *(const bf16x8*)&Bs[nt * 16 + c][kk + g * 8];
                acc[nt] = __builtin_amdgcn_mfma_f32_16x16x32_bf16(af, bfr, acc[nt], 0, 0, 0);
            }
        }
    }

    const float qscale = 1.4426950408889634f * 0.17677669529663687f; // log2e/sqrt(32)
    const float invf = exp2f(-0.83048202372184f * (float)c);          // 10000^(-c/16)
    #pragma unroll
    for (int r = 0; r < 4; ++r) {
        int m = m0 + wid * 16 + g * 4 + r;
        int b = m >> 12, s = m & (SEQ - 1);
        float sn, cs;
        sincosf((float)s * invf, &sn, &cs);
        if (n0 < 256) {
            #pragma unroll
            for (int np = 0; np < 4; np += 2) {
                int h = (n0 + np * 16) >> 5;
                float x1 = acc[np][r], x2 = acc[np + 1][r];
                float y1 = (x1 * cs - x2 * sn) * qscale;
                float y2 = (x2 * cs + x1 * sn) * qscale;
                size_t base = ((size_t)(b * NHEAD + h) * SEQ + s) * HDIM;
                qws[base + c] = (bf16)y1;
                qws[base + 16 + c] = (bf16)y2;
            }
        } else if (n0 < 384) {
            #pragma unroll
            for (int np = 0; np < 4; np += 2) {
                int kh = (n0 - 256 + np * 16) >> 5;
                float x1 = acc[np][r], x2 = acc[np + 1][r];
                float y1 = x1 * cs - x2 * sn;
                float y2 = x2 * cs + x1 * sn;
                size_t base = ((size_t)(b * NKVH + kh) * SEQ + s) * HDIM;
                kws[base + c] = (bf16)y1;
                kws[base + 16 + c] = (bf16)y2;
            }
        } else {
            #pragma unroll
            for (int nt = 0; nt < 4; ++nt) {
                int ng = n0 + nt * 16 + c - 384;
                int vh = ng >> 5, d = ng & 31;
                vtws[((size_t)(b * NKVH + vh) * HDIM + d) * SEQ + s] = (bf16)acc[nt][r];
            }
        }
    }
}

// ---------------------------------------------------------------------------
// Kernel 2: causal flash attention, no-max softmax, K-SPLIT x2.
// 512 threads = 8 waves: 4 query-slots x 2 K-split waves.  Partials (O^T, l)
// are purely additive (no running max) -> combine through LDS, normalize once.
// Ping-pong register prefetch (no rotation movs); diagonal tile peeled;
// raw v_exp_f32.  Tile pairing {T, 63-T} balances causal work per block.
// ---------------------------------------------------------------------------
#define LOADF(D0, D1, D2, D3, KP, VP)                                          \
  do {                                                                         \
    D0 = *(const bf16x8*)((KP) + koffA);                                       \
    D1 = *(const bf16x8*)((KP) + koffB);                                       \
    D2 = *(const bf16x8*)((VP) + voffA);                                       \
    D3 = *(const bf16x8*)((VP) + voffB);                                       \
  } while (0)

#define ATTN_STEP(K0F, K1F, V0F, V1F, DIAG)                                    \
  do {                                                                         \
    f32x4 st0 = __builtin_amdgcn_mfma_f32_16x16x32_bf16((K0F), qf, zf, 0, 0, 0);\
    f32x4 st1 = __builtin_amdgcn_mfma_f32_16x16x32_bf16((K1F), qf, zf, 0, 0, 0);\
    if (DIAG) {                                                                \
      if ((q0 & 16) == 0) {                                                    \
        _Pragma("unroll") for (int r = 0; r < 4; ++r) {                        \
          if (g * 4 + r > c) st0[r] = -1e30f;                                  \
          st1[r] = -1e30f;                                                     \
        }                                                                      \
      } else {                                                                 \
        _Pragma("unroll") for (int r = 0; r < 4; ++r)                          \
          if (g * 4 + r > c) st1[r] = -1e30f;                                  \
      }                                                                        \
    }                                                                          \
    float p0 = fexp2(st0[0]), p1 = fexp2(st0[1]);                              \
    float p2 = fexp2(st0[2]), p3 = fexp2(st0[3]);                              \
    float p4 = fexp2(st1[0]), p5 = fexp2(st1[1]);                              \
    float p6 = fexp2(st1[2]), p7 = fexp2(st1[3]);                              \
    uint32_t P0, P1, P2, P3;                                                   \
    asm("v_cvt_pk_bf16_f32 %0, %1, %2" : "=v"(P0) : "v"(p0), "v"(p1));         \
    asm("v_cvt_pk_bf16_f32 %0, %1, %2" : "=v"(P1) : "v"(p2), "v"(p3));         \
    asm("v_cvt_pk_bf16_f32 %0, %1, %2" : "=v"(P2) : "v"(p4), "v"(p5));         \
    asm("v_cvt_pk_bf16_f32 %0, %1, %2" : "=v"(P3) : "v"(p6), "v"(p7));         \
    uint32_t a0 = (uint32_t)__shfl((int)P0, srcA), a2 = (uint32_t)__shfl((int)P2, srcA); \
    uint32_t b0 = (uint32_t)__shfl((int)P1, srcA), b2 = (uint32_t)__shfl((int)P3, srcA); \
    uint32_t c0 = (uint32_t)__shfl((int)P0, srcB), c2 = (uint32_t)__shfl((int)P2, srcB); \
    uint32_t e0 = (uint32_t)__shfl((int)P1, srcB), e2 = (uint32_t)__shfl((int)P3, srcB); \
    union { uint32_t u[4]; bf16x8 v; } pb;                                     \
    pb.u[0] = hi ? a2 : a0;  pb.u[1] = hi ? b2 : b0;                           \
    pb.u[2] = hi ? c2 : c0;  pb.u[3] = hi ? e2 : e0;                           \
    o0 = __builtin_amdgcn_mfma_f32_16x16x32_bf16((V0F), pb.v, o0, 0, 0, 0);    \
    o1 = __builtin_amdgcn_mfma_f32_16x16x32_bf16((V1F), pb.v, o1, 0, 0, 0);    \
    o2 = __builtin_amdgcn_mfma_f32_16x16x32_bf16(onesf.v, pb.v, o2, 0, 0, 0);  \
  } while (0)

__global__ __launch_bounds__(512, 4) void attn_fwd(
    const bf16* __restrict__ qws, const bf16* __restrict__ kws,
    const bf16* __restrict__ vtws, bf16* __restrict__ att)
{
    __shared__ float part[8][16][35];
    __shared__ float lpart[8][16];
    const int t = threadIdx.x;
    const int w = t >> 6, lane = t & 63;
    const int g = lane >> 4, c = lane & 15;
    const int qs = w >> 1, s = w & 1;        // query slot / K-split index
    const int h = blockIdx.y, b = blockIdx.z;
    const int kvh = h >> 1;                  // GROUPS=2 repeat_interleave
    const char* kbase = (const char*)(kws + (size_t)(b * NKVH + kvh) * SEQ * HDIM);
    const char* vbase = (const char*)(vtws + (size_t)(b * NKVH + kvh) * HDIM * SEQ);
    const int koffA = (c * HDIM + g * 8) * 2, koffB = koffA + 16 * HDIM * 2;
    const int voffA = (c * SEQ + g * 8) * 2,  voffB = voffA + 16 * SEQ * 2;
    const int srcA = ((g & 1) * 2) * 16 + c, srcB = srcA + 16;
    const bool hi = (g >= 2);
    const f32x4 zf = {0.f, 0.f, 0.f, 0.f};
    union { uint32_t u[4]; bf16x8 v; } onesf;
    onesf.u[0] = onesf.u[1] = onesf.u[2] = onesf.u[3] = 0x3F803F80u;

    #pragma unroll 1
    for (int ti = 0; ti < 2; ++ti) {
        const int T = (ti == 0) ? (int)blockIdx.x : 63 - (int)blockIdx.x;
        const int q0 = T * 64 + qs * 16;
        const bf16* Qp = qws + ((size_t)(b * NHEAD + h) * SEQ + q0) * HDIM;
        bf16x8 qf = *(const bf16x8*)&Qp[(size_t)c * HDIM + g * 8];

        f32x4 o0 = zf, o1 = zf, o2 = zf;
        const int i_d = q0 >> 5;             // diagonal chunk index

        if (s <= i_d) {
            const char* kP = kbase + s * 2048;   // chunk s (32 keys = 2KB of K)
            const char* vP = vbase + s * 64;     // 32 keys = 64B per V row
            bf16x8 A0, A1, A2, A3, B0, B1, B2, B3;
            LOADF(A0, A1, A2, A3, kP, vP);
            int i = s;
            #pragma unroll 1
            for (; i + 2 < i_d; i += 4) {
                LOADF(B0, B1, B2, B3, kP + 4096, vP + 128);
                ATTN_STEP(A0, A1, A2, A3, 0);
                kP += 8192; vP += 256;
                LOADF(A0, A1, A2, A3, kP, vP);
                ATTN_STEP(B0, B1, B2, B3, 0);
            }
            if (i < i_d) {
                if (s == (i_d & 1)) {
                    const int dlt = i_d - i;         // 1 or 2
                    LOADF(B0, B1, B2, B3, kP + dlt * 2048, vP + dlt * 64);
                    ATTN_STEP(A0, A1, A2, A3, 0);
                    ATTN_STEP(B0, B1, B2, B3, 1);
                } else {
                    ATTN_STEP(A0, A1, A2, A3, 0);
                }
            } else {
                if (s == (i_d & 1)) ATTN_STEP(A0, A1, A2, A3, 1);
            }
        }

        // write partials (all waves, even idle ones: zeros)
        #pragma unroll
        for (int r = 0; r < 4; ++r) {
            part[w][c][g * 4 + r]      = o0[r];
            part[w][c][16 + g * 4 + r] = o1[r];
        }
        if (g == 0) lpart[w][c] = o2[0];
        __syncthreads();

        // combine + normalize + store: wave w handles slot qs, rows [s*8, s*8+8)
        {
            const int rq = s * 8 + (lane >> 3);
            const int d0 = (lane & 7) * 4;
            float l = lpart[qs * 2][rq] + lpart[qs * 2 + 1][rq];
            float inv = 1.0f / l;
            float f0 = (part[qs * 2][rq][d0 + 0] + part[qs * 2 + 1][rq][d0 + 0]) * inv;
            float f1 = (part[qs * 2][rq][d0 + 1] + part[qs * 2 + 1][rq][d0 + 1]) * inv;
            float f2 = (part[qs * 2][rq][d0 + 2] + part[qs * 2 + 1][rq][d0 + 2]) * inv;
            float f3 = (part[qs * 2][rq][d0 + 3] + part[qs * 2 + 1][rq][d0 + 3]) * inv;
            uint32_t u0 = pack_bf16(f0, f1);
            uint32_t u1 = pack_bf16(f2, f3);
            size_t base = ((size_t)b * SEQ + q0 + rq) * HID + h * HDIM + d0;
            *(uint2*)&att[base] = make_uint2(u0, u1);
        }
        __syncthreads();
    }
}

// ---------------------------------------------------------------------------
// Kernel 3: output projection (unchanged from R2).
// ---------------------------------------------------------------------------
__global__ __launch_bounds__(256) void out_proj(
    const bf16* __restrict__ att, const float* __restrict__ Wo,
    float* __restrict__ out)
{
    __shared__ bf16 As[64][136];
    __shared__ bf16 Bs[64][136];
    const int t = threadIdx.x;
    const int wid = t >> 6, lane = t & 63;
    const int g = lane >> 4, c = lane & 15;
    const int n0 = blockIdx.x * 64;
    const int m0 = blockIdx.y * 64;

    const f32x4 zf = {0.f, 0.f, 0.f, 0.f};
    f32x4 acc[4] = {zf, zf, zf, zf};

    const int c4 = t & 31;
    const int rb = t >> 5;

    for (int ks = 0; ks < 256; ks += 128) {
        __syncthreads();
        #pragma unroll
        for (int i = 0; i < 8; ++i) {
            int row = i * 8 + rb;
            ushort4 v = *(const ushort4*)&att[(size_t)(m0 + row) * HID + ks + c4 * 4];
            *(ushort4*)&As[row][c4 * 4] = v;
        }
        #pragma unroll
        for (int i = 0; i < 8; ++i) {
            int row = i * 8 + rb;
            float4 v = *(const float4*)&Wo[(size_t)(n0 + row) * HID + ks + c4 * 4];
            ushort4 w; w.x = bfbits(v.x); w.y = bfbits(v.y); w.z = bfbits(v.z); w.w = bfbits(v.w);
            *(ushort4*)&Bs[row][c4 * 4] = w;
        }
        __syncthreads();
        #pragma unroll
        for (int kk = 0; kk < 128; kk += 32) {
            bf16x8 af = *(const bf16x8*)&As[wid * 16 + c][kk + g * 8];
            #pragma unroll
            for (int nt = 0; nt < 4; ++nt) {
                bf16x8 bfr = *(const bf16x8*)&Bs[nt * 16 + c][kk + g * 8];
                acc[nt] = __builtin_amdgcn_mfma_f32_16x16x32_bf16(af, bfr, acc[nt], 0, 0, 0);
            }
        }
    }

    #pragma unroll
    for (int nt = 0; nt < 4; ++nt) {
        #pragma unroll
        for (int r = 0; r < 4; ++r) {
            int m = m0 + wid * 16 + g * 4 + r;
            out[(size_t)m * HID + n0 + nt * 16 + c] = acc[nt][r];
        }
    }
}

extern "C" void kernel_launch(void* const* d_in, const int* in_sizes, int n_in,
                              void* d_out, int out_size, void* d_ws, size_t ws_size,
                              hipStream_t stream) {
    const float* hs = (const float*)d_in[0];
    const float* Wq = (const float*)d_in[1];
    const float* Wk = (const float*)d_in[2];
    const float* Wv = (const float*)d_in[3];
    const float* Wo = (const float*)d_in[4];
    char* ws = (char*)d_ws;
    bf16* qws  = (bf16*)(ws);                 // [2][8][4096][32]  4,194,304 B
    bf16* kws  = (bf16*)(ws + 4194304);       // [2][4][4096][32]  2,097,152 B
    bf16* vtws = (bf16*)(ws + 6291456);       // [2][4][32][4096]  2,097,152 B
    bf16* att  = (bf16*)(ws + 8388608);       // [2][4096][256]    4,194,304 B

    qkv_proj<<<dim3(8, 128), 256, 0, stream>>>(hs, Wq, Wk, Wv, qws, kws, vtws);
    attn_fwd<<<dim3(32, NHEAD, NB), 512, 0, stream>>>(qws, kws, vtws, att);
    out_proj<<<dim3(4, 128), 256, 0, stream>>>(att, Wo, (float*)d_out);
}